// Round 6
// baseline (86.067 us; speedup 1.0000x reference)
//
#include <hip/hip_runtime.h>
#include <stdint.h>

#define PP     16
#define LRDIM  256
#define DDIM   1024
#define LN_EPS 1e-5f

typedef __attribute__((ext_vector_type(8))) short  short8;
typedef __attribute__((ext_vector_type(4))) float  f32x4;

__device__ __forceinline__ uint32_t bf16_rne(float f) {
    uint32_t u = __builtin_bit_cast(uint32_t, f);
    return (u + 0x7fffu + ((u >> 16) & 1u)) >> 16;
}
__device__ __forceinline__ float bf_lo(uint32_t u) {
    return __builtin_bit_cast(float, u << 16);
}
__device__ __forceinline__ float bf_hi(uint32_t u) {
    return __builtin_bit_cast(float, u & 0xffff0000u);
}

// async global->LDS, 16 B per lane (global_load_lds_dwordx4)
typedef __attribute__((address_space(3))) uint32_t       lds_u32;
typedef const __attribute__((address_space(1))) uint32_t glb_u32;
__device__ __forceinline__ void gload_lds16(const void* g, void* l) {
    __builtin_amdgcn_global_load_lds((glb_u32*)g, (lds_u32*)l, 16, 0, 0);
}

// ---------------------------------------------------------------------------
// K1 fused prep.
// blocks [0,512):  table2b[p][c][j] = bf16(sum_i pe[p][i][j] * bt[c][i]),
//                  8 c-rows/block; bt reads wave-uniform -> scalar loads.
// blocks [512,640): repack W_up [D][LR] f32 -> bf16 MFMA B-frags, KS-MAJOR:
//                  wb[((ks*64)+nfg)*64 + l] = W[nfg*16+(l&15)][ks*32+(l>>4)*8+..7]
//                  (each ks-slice = contiguous 64 KB for async staging)
// ---------------------------------------------------------------------------
__global__ __launch_bounds__(256) void k_prep(const float* __restrict__ bt,
                                              const float* __restrict__ pe,
                                              const float* __restrict__ W,
                                              unsigned short* __restrict__ t2b,
                                              uint4* __restrict__ wb) {
    if (blockIdx.x < 512) {
        const int p  = blockIdx.x >> 5;          // 0..15
        const int c0 = (blockIdx.x & 31) << 3;   // 0..248
        const int j  = threadIdx.x;
        const float* pep = pe + (size_t)p * LRDIM * LRDIM;
        float a[8];
#pragma unroll
        for (int r = 0; r < 8; ++r) a[r] = 0.f;
#pragma unroll 4
        for (int i = 0; i < LRDIM; ++i) {
            const float v = pep[i * LRDIM + j];          // coalesced across j
#pragma unroll
            for (int r = 0; r < 8; ++r)                   // uniform -> s_loads
                a[r] = fmaf(v, bt[(c0 + r) * LRDIM + i], a[r]);
        }
#pragma unroll
        for (int r = 0; r < 8; ++r)
            t2b[(size_t)((p << 8) + c0 + r) * LRDIM + j] =
                (unsigned short)bf16_rne(a[r]);
    } else {
        const int gt  = (blockIdx.x - 512) * 256 + threadIdx.x;  // 0..32767
        const int l   = gt & 63;
        const int ks  = (gt >> 6) & 7;
        const int nfg = gt >> 9;                                  // 0..63
        const int n   = nfg * 16 + (l & 15);
        const int k   = ks * 32 + (l >> 4) * 8;
        const float* src = W + (size_t)n * LRDIM + k;
        uint32_t r[4];
#pragma unroll
        for (int q = 0; q < 4; ++q) {
            const uint32_t lo = bf16_rne(src[2 * q + 0]);
            const uint32_t hi = bf16_rne(src[2 * q + 1]);
            r[q] = lo | (hi << 16);
        }
        wb[((ks << 6) + nfg) * 64 + l] = make_uint4(r[0], r[1], r[2], r[3]);
    }
}

// ---------------------------------------------------------------------------
// K2: gather-sum. One wave per token; lane owns lr = 4l..4l+3.
// A[tok][256] bf16 out (uint2 per lane). 16 independent masked loads/lane.
// ---------------------------------------------------------------------------
__global__ __launch_bounds__(256) void k_gather(const int* __restrict__ ids,
                                                const unsigned short* __restrict__ t2b,
                                                uint2* __restrict__ Aq,
                                                int ntok) {
    const int wid = (blockIdx.x << 2) + (threadIdx.x >> 6);
    const int l   = threadIdx.x & 63;
    if (wid >= ntok) return;

    const int myid = (l < PP) ? ids[(size_t)wid * PP + l] : -1;

    float a0 = 0.f, a1 = 0.f, a2 = 0.f, a3 = 0.f;
#pragma unroll
    for (int p = 0; p < PP; ++p) {
        const int   id  = __shfl(myid, p);
        const float msk = (id >= 0) ? 1.f : 0.f;
        const uint2 v = *(const uint2*)(t2b +
                          ((size_t)((p << 8) + (id & 255)) << 8) + (l << 2));
        a0 = fmaf(msk, bf_lo(v.x), a0);
        a1 = fmaf(msk, bf_hi(v.x), a1);
        a2 = fmaf(msk, bf_lo(v.y), a2);
        a3 = fmaf(msk, bf_hi(v.y), a3);
    }
    uint2 pk;
    pk.x = bf16_rne(a0) | (bf16_rne(a1) << 16);
    pk.y = bf16_rne(a2) | (bf16_rne(a3) << 16);
    Aq[(size_t)wid * 64 + l] = pk;
}

// ---------------------------------------------------------------------------
// K3: MFMA GEMM + fused bias/LN, async-pipelined B.
// Block = 512 thr (8 waves), 32 tokens x N=1024; wave w owns cols
// [w*128, w*128+128): acc[m2][nf] = 64 regs. B streams through a 2x64 KB LDS
// double buffer via global_load_lds (stage ks+1 issued BEFORE computing ks;
// __syncthreads' vmcnt(0) drain lands after compute -> latency hidden).
// A-frags read global-direct (16 KB tile -> L1 after first wave).
// ---------------------------------------------------------------------------
__global__ __launch_bounds__(512, 1) void k_gemm(const unsigned short* __restrict__ A,
                                                 const uint4* __restrict__ wb,
                                                 const float* __restrict__ b_up,
                                                 const float* __restrict__ gamma,
                                                 const float* __restrict__ beta,
                                                 float* __restrict__ out,
                                                 int ntok) {
    __shared__ __align__(16) unsigned char Bs[2][65536];   // 128 KB B dbuf
    __shared__ float ln_s[8][32];
    __shared__ float ln_ss[8][32];

    const int t    = threadIdx.x;
    const int w    = t >> 6;        // wave 0..7
    const int l    = t & 63;
    const int lo4  = l & 15;
    const int hi2  = l >> 4;        // 0..3
    const int tok0 = blockIdx.x << 5;

    // stage one ks-slice (64 KB, contiguous in wb) into Bs[buf]
    // thread t: 8 chunks of 16 B at offsets t*16 + h*8192 (lane-linear dest)
#define STAGE_B(ks_, buf_)                                                  \
    {                                                                       \
        const uint4* _src = wb + (((ks_) << 12) + t);                       \
        unsigned char* _dst = &Bs[(buf_)][0] + (t << 4);                    \
        _Pragma("unroll")                                                   \
        for (int h = 0; h < 8; ++h)                                         \
            gload_lds16(_src + h * 512, _dst + h * 8192);                   \
    }

    f32x4 acc[2][8];
#pragma unroll
    for (int m2 = 0; m2 < 2; ++m2)
#pragma unroll
        for (int nf = 0; nf < 8; ++nf) {
            f32x4 z = {0.f, 0.f, 0.f, 0.f};
            acc[m2][nf] = z;
        }

    const unsigned short* Abase = A + ((size_t)tok0 << 8);

    STAGE_B(0, 0);
    __syncthreads();                 // buf0 ready

#pragma unroll
    for (int ks = 0; ks < 8; ++ks) {
        const int cur = ks & 1;
        if (ks < 7) STAGE_B(ks + 1, cur ^ 1);   // async, rides under compute

        short8 af[2];
#pragma unroll
        for (int m2 = 0; m2 < 2; ++m2) {
            const int row = (m2 << 4) + lo4;
            af[m2] = *(const short8*)(Abase + ((size_t)row << 8) + (ks << 5) + (hi2 << 3));
        }
#pragma unroll
        for (int nf = 0; nf < 8; ++nf) {
            const short8 bfr = *(const short8*)(&Bs[cur][((((w << 3) + nf) << 6) + l) << 4]);
            acc[0][nf] = __builtin_amdgcn_mfma_f32_16x16x32_bf16(af[0], bfr, acc[0][nf], 0, 0, 0);
            acc[1][nf] = __builtin_amdgcn_mfma_f32_16x16x32_bf16(af[1], bfr, acc[1][nf], 0, 0, 0);
        }
        __syncthreads();             // drains vmcnt (next buf staged) + barrier
    }

    // ---- epilogue: +bias, per-token stats (token slot q = m2*4 + r) ----
    float s_[8], ss_[8];
#pragma unroll
    for (int q = 0; q < 8; ++q) { s_[q] = 0.f; ss_[q] = 0.f; }

#pragma unroll
    for (int nf = 0; nf < 8; ++nf) {
        const int col = (w << 7) + (nf << 4) + lo4;
        const float bu = b_up[col];
#pragma unroll
        for (int m2 = 0; m2 < 2; ++m2) {
            f32x4 v = acc[m2][nf];
            v.x += bu; v.y += bu; v.z += bu; v.w += bu;
            acc[m2][nf] = v;
            const int q0 = m2 * 4;
            s_[q0 + 0] += v.x; ss_[q0 + 0] += v.x * v.x;
            s_[q0 + 1] += v.y; ss_[q0 + 1] += v.y * v.y;
            s_[q0 + 2] += v.z; ss_[q0 + 2] += v.z * v.z;
            s_[q0 + 3] += v.w; ss_[q0 + 3] += v.w * v.w;
        }
    }
#pragma unroll
    for (int off = 1; off < 16; off <<= 1)
#pragma unroll
        for (int q = 0; q < 8; ++q) {
            s_[q]  += __shfl_xor(s_[q], off);
            ss_[q] += __shfl_xor(ss_[q], off);
        }
    if (lo4 == 0) {
#pragma unroll
        for (int q = 0; q < 8; ++q) {
            const int tl = (q >> 2) * 16 + hi2 * 4 + (q & 3);
            ln_s[w][tl]  = s_[q];
            ln_ss[w][tl] = ss_[q];
        }
    }
    __syncthreads();

    float mu_[8], inv_[8];
#pragma unroll
    for (int q = 0; q < 8; ++q) {
        const int tl = (q >> 2) * 16 + hi2 * 4 + (q & 3);
        float S = 0.f, SS = 0.f;
#pragma unroll
        for (int ww = 0; ww < 8; ++ww) { S += ln_s[ww][tl]; SS += ln_ss[ww][tl]; }
        const float mu  = S * (1.f / DDIM);
        const float var = SS * (1.f / DDIM) - mu * mu;
        mu_[q]  = mu;
        inv_[q] = rsqrtf(var + LN_EPS);
    }

    // ---- write out ----
#pragma unroll
    for (int nf = 0; nf < 8; ++nf) {
        const int col = (w << 7) + (nf << 4) + lo4;
        const float g  = gamma[col];
        const float bb = beta[col];
#pragma unroll
        for (int m2 = 0; m2 < 2; ++m2) {
            const f32x4 v = acc[m2][nf];
#pragma unroll
            for (int r = 0; r < 4; ++r) {
                const int q   = m2 * 4 + r;
                const int tl  = m2 * 16 + hi2 * 4 + r;
                const int tok = tok0 + tl;
                if (tok < ntok)
                    out[(size_t)tok * DDIM + col] = (v[r] - mu_[q]) * inv_[q] * g + bb;
            }
        }
    }
#undef STAGE_B
}

// ---------------------------------------------------------------------------
extern "C" void kernel_launch(void* const* d_in, const int* in_sizes, int n_in,
                              void* d_out, int out_size, void* d_ws, size_t ws_size,
                              hipStream_t stream) {
    const int*   ids   = (const int*)  d_in[0];
    const float* bt    = (const float*)d_in[1];
    const float* pe    = (const float*)d_in[2];
    const float* W     = (const float*)d_in[3];
    const float* b_up  = (const float*)d_in[4];
    const float* gamma = (const float*)d_in[5];
    const float* beta  = (const float*)d_in[6];
    float* out = (float*)d_out;

    const int ntok = in_sizes[0] / PP;   // B*S = 16384

    char* ws = (char*)d_ws;
    unsigned short* t2b = (unsigned short*)(ws);        // 2 MB
    uint4*          wbb = (uint4*)(ws + (2 << 20));     // 512 KB (ks-major)
    unsigned short* Abf = (unsigned short*)(ws + (3 << 20)); // ntok*256*2 = 8 MB
    uint2*          Aq  = (uint2*)Abf;

    hipLaunchKernelGGL(k_prep, dim3(640), dim3(256), 0, stream, bt, pe, W, t2b, wbb);
    hipLaunchKernelGGL(k_gather, dim3((ntok + 3) / 4), dim3(256), 0, stream,
                       ids, t2b, Aq, ntok);
    hipLaunchKernelGGL(k_gemm, dim3((ntok + 31) / 32), dim3(512), 0, stream,
                       Abf, wbb, b_up, gamma, beta, out, ntok);
}

// Round 7
// 85.572 us; speedup vs baseline: 1.0058x; 1.0058x over previous
//
#include <hip/hip_runtime.h>
#include <stdint.h>

#define PP     16
#define LRDIM  256
#define DDIM   1024
#define LN_EPS 1e-5f

typedef __attribute__((ext_vector_type(8))) short  short8;
typedef __attribute__((ext_vector_type(4))) float  f32x4;

__device__ __forceinline__ uint32_t bf16_rne(float f) {
    uint32_t u = __builtin_bit_cast(uint32_t, f);
    return (u + 0x7fffu + ((u >> 16) & 1u)) >> 16;
}
__device__ __forceinline__ float bf_lo(uint32_t u) {
    return __builtin_bit_cast(float, u << 16);
}
__device__ __forceinline__ float bf_hi(uint32_t u) {
    return __builtin_bit_cast(float, u & 0xffff0000u);
}

// async global->LDS, 16 B per lane (global_load_lds_dwordx4)
typedef __attribute__((address_space(3))) uint32_t       lds_u32;
typedef const __attribute__((address_space(1))) uint32_t glb_u32;
__device__ __forceinline__ void gload_lds16(const void* g, void* l) {
    __builtin_amdgcn_global_load_lds((glb_u32*)g, (lds_u32*)l, 16, 0, 0);
}

// ---------------------------------------------------------------------------
// K1 fused prep.
// blocks [0,512):  table2b[p][c][j] = bf16(sum_i pe[p][i][j] * bt[c][i]),
//                  8 c-rows/block; bt reads wave-uniform -> scalar loads.
// blocks [512,640): repack W_up [D][LR] f32 -> bf16 MFMA B-frags, KS-MAJOR:
//                  wb[((ks*64)+nfg)*64 + l] = W[nfg*16+(l&15)][ks*32+(l>>4)*8+..7]
// ---------------------------------------------------------------------------
__global__ __launch_bounds__(256) void k_prep(const float* __restrict__ bt,
                                              const float* __restrict__ pe,
                                              const float* __restrict__ W,
                                              unsigned short* __restrict__ t2b,
                                              uint4* __restrict__ wb) {
    if (blockIdx.x < 512) {
        const int p  = blockIdx.x >> 5;          // 0..15
        const int c0 = (blockIdx.x & 31) << 3;   // 0..248
        const int j  = threadIdx.x;
        const float* pep = pe + (size_t)p * LRDIM * LRDIM;
        float a[8];
#pragma unroll
        for (int r = 0; r < 8; ++r) a[r] = 0.f;
#pragma unroll 4
        for (int i = 0; i < LRDIM; ++i) {
            const float v = pep[i * LRDIM + j];          // coalesced across j
#pragma unroll
            for (int r = 0; r < 8; ++r)                   // uniform -> s_loads
                a[r] = fmaf(v, bt[(c0 + r) * LRDIM + i], a[r]);
        }
#pragma unroll
        for (int r = 0; r < 8; ++r)
            t2b[(size_t)((p << 8) + c0 + r) * LRDIM + j] =
                (unsigned short)bf16_rne(a[r]);
    } else {
        const int gt  = (blockIdx.x - 512) * 256 + threadIdx.x;  // 0..32767
        const int l   = gt & 63;
        const int ks  = (gt >> 6) & 7;
        const int nfg = gt >> 9;                                  // 0..63
        const int n   = nfg * 16 + (l & 15);
        const int k   = ks * 32 + (l >> 4) * 8;
        const float* src = W + (size_t)n * LRDIM + k;
        uint32_t r[4];
#pragma unroll
        for (int q = 0; q < 4; ++q) {
            const uint32_t lo = bf16_rne(src[2 * q + 0]);
            const uint32_t hi = bf16_rne(src[2 * q + 1]);
            r[q] = lo | (hi << 16);
        }
        wb[((ks << 6) + nfg) * 64 + l] = make_uint4(r[0], r[1], r[2], r[3]);
    }
}

// ---------------------------------------------------------------------------
// K2: gather-sum. One wave per token; lane owns lr = 4l..4l+3.
// Output A[tok][256] bf16, PRE-SWIZZLED within each 512-B row:
// uint2 element e stored at e ^ ((tok&7)<<1)  (byte ^= (tok&7)<<4), so k_gemm
// can stage it linearly with global_load_lds and ds_read with the same XOR
// (rule #21: inverse-swizzled source + swizzled read, linear DMA dest).
// ---------------------------------------------------------------------------
__global__ __launch_bounds__(256) void k_gather(const int* __restrict__ ids,
                                                const unsigned short* __restrict__ t2b,
                                                uint2* __restrict__ Aq,
                                                int ntok) {
    const int wid = (blockIdx.x << 2) + (threadIdx.x >> 6);
    const int l   = threadIdx.x & 63;
    if (wid >= ntok) return;

    const int myid = (l < PP) ? ids[(size_t)wid * PP + l] : -1;

    float a0 = 0.f, a1 = 0.f, a2 = 0.f, a3 = 0.f;
#pragma unroll
    for (int p = 0; p < PP; ++p) {
        const int   id  = __shfl(myid, p);
        const float msk = (id >= 0) ? 1.f : 0.f;
        const uint2 v = *(const uint2*)(t2b +
                          ((size_t)((p << 8) + (id & 255)) << 8) + (l << 2));
        a0 = fmaf(msk, bf_lo(v.x), a0);
        a1 = fmaf(msk, bf_hi(v.x), a1);
        a2 = fmaf(msk, bf_lo(v.y), a2);
        a3 = fmaf(msk, bf_hi(v.y), a3);
    }
    uint2 pk;
    pk.x = bf16_rne(a0) | (bf16_rne(a1) << 16);
    pk.y = bf16_rne(a2) | (bf16_rne(a3) << 16);
    Aq[((size_t)wid << 6) + (l ^ ((wid & 7) << 1))] = pk;   // swizzled store
}

// ---------------------------------------------------------------------------
// K3: MFMA GEMM + fused bias/LN. BARRIER-FREE K-loop.
// Block = 512 thr (8 waves), 32 tokens x N=1024; wave w owns cols
// [w*128, w*128+128): acc[m2][nf] = 64 regs (AGPR).
// A: 16 KB LDS, staged ONCE via global_load_lds (linear dest, source image
//    pre-swizzled by k_gather); fragment ds_reads XOR-swizzled -> bank-uniform.
// B: register rolling prefetch (4x uint4 window) from ks-major wb in L2;
//    per-use vmcnt waits only, NO barriers, NO LDS port pressure.
// __launch_bounds__(512,4): 128-reg cap (acc 64 + win 16 + af 8 + addr ~25
// fits) -> 2 blocks/CU = 4 waves/SIMD to cover ~240cy L2 latency.
// ---------------------------------------------------------------------------
__global__ __launch_bounds__(512, 4) void k_gemm(const unsigned short* __restrict__ A,
                                                 const uint4* __restrict__ wb,
                                                 const float* __restrict__ b_up,
                                                 const float* __restrict__ gamma,
                                                 const float* __restrict__ beta,
                                                 float* __restrict__ out,
                                                 int ntok) {
    __shared__ __align__(16) unsigned char As[32 * 512];   // 16 KB swz A tile
    __shared__ float ln_s[8][32];
    __shared__ float ln_ss[8][32];

    const int t    = threadIdx.x;
    const int w    = t >> 6;        // wave 0..7
    const int l    = t & 63;
    const int lo4  = l & 15;
    const int hi2  = l >> 4;        // 0..3
    const int tok0 = blockIdx.x << 5;

    // ---- stage A tile once: 1024 16B-chunks, lane-linear dest ----
    {
        const uint4* asrc = (const uint4*)(A + ((size_t)tok0 << 8));
        gload_lds16(asrc + t,       As + (t << 4));
        gload_lds16(asrc + 512 + t, As + 8192 + (t << 4));
    }

    f32x4 acc[2][8];
#pragma unroll
    for (int m2 = 0; m2 < 2; ++m2)
#pragma unroll
        for (int nf = 0; nf < 8; ++nf) {
            f32x4 z = {0.f, 0.f, 0.f, 0.f};
            acc[m2][nf] = z;
        }

    // B pointer: wb[((ks<<6) + w*8 + nf)*64 + l]
    const uint4* wpB = wb + ((size_t)(w << 9) + l);
#define BLD(ks_, nf_) wpB[((ks_) << 12) + ((nf_) << 6)]

    uint4 bP[4];
#pragma unroll
    for (int j = 0; j < 4; ++j) bP[j] = BLD(0, j);

    __syncthreads();                 // A tile ready (drains the 2 DMA loads)

    // swizzle constants for A-frag reads: row = m2*16+lo4, r7 = row&7 = lo4&7
    const int swz = (lo4 & 7) << 4;

#pragma unroll
    for (int ks = 0; ks < 8; ++ks) {
        short8 af[2];
#pragma unroll
        for (int m2 = 0; m2 < 2; ++m2) {
            const int row = (m2 << 4) + lo4;
            af[m2] = *(const short8*)(As + (row << 9) +
                                      (((ks << 6) + (hi2 << 4)) ^ swz));
        }
        // first half: nf 0..3 from bP, then reload bP with second half
#pragma unroll
        for (int j = 0; j < 4; ++j) {
            const short8 bfr = __builtin_bit_cast(short8, bP[j]);
            acc[0][j] = __builtin_amdgcn_mfma_f32_16x16x32_bf16(af[0], bfr, acc[0][j], 0, 0, 0);
            acc[1][j] = __builtin_amdgcn_mfma_f32_16x16x32_bf16(af[1], bfr, acc[1][j], 0, 0, 0);
        }
#pragma unroll
        for (int j = 0; j < 4; ++j) bP[j] = BLD(ks, 4 + j);
        // second half: nf 4..7, then prefetch next ks's first half
#pragma unroll
        for (int j = 0; j < 4; ++j) {
            const short8 bfr = __builtin_bit_cast(short8, bP[j]);
            acc[0][4 + j] = __builtin_amdgcn_mfma_f32_16x16x32_bf16(af[0], bfr, acc[0][4 + j], 0, 0, 0);
            acc[1][4 + j] = __builtin_amdgcn_mfma_f32_16x16x32_bf16(af[1], bfr, acc[1][4 + j], 0, 0, 0);
        }
        if (ks < 7) {
#pragma unroll
            for (int j = 0; j < 4; ++j) bP[j] = BLD(ks + 1, j);
        }
    }
#undef BLD

    // ---- epilogue: +bias, per-token stats (token slot q = m2*4 + r) ----
    float s_[8], ss_[8];
#pragma unroll
    for (int q = 0; q < 8; ++q) { s_[q] = 0.f; ss_[q] = 0.f; }

#pragma unroll
    for (int nf = 0; nf < 8; ++nf) {
        const int col = (w << 7) + (nf << 4) + lo4;
        const float bu = b_up[col];
#pragma unroll
        for (int m2 = 0; m2 < 2; ++m2) {
            f32x4 v = acc[m2][nf];
            v.x += bu; v.y += bu; v.z += bu; v.w += bu;
            acc[m2][nf] = v;
            const int q0 = m2 * 4;
            s_[q0 + 0] += v.x; ss_[q0 + 0] += v.x * v.x;
            s_[q0 + 1] += v.y; ss_[q0 + 1] += v.y * v.y;
            s_[q0 + 2] += v.z; ss_[q0 + 2] += v.z * v.z;
            s_[q0 + 3] += v.w; ss_[q0 + 3] += v.w * v.w;
        }
    }
#pragma unroll
    for (int off = 1; off < 16; off <<= 1)
#pragma unroll
        for (int q = 0; q < 8; ++q) {
            s_[q]  += __shfl_xor(s_[q], off);
            ss_[q] += __shfl_xor(ss_[q], off);
        }
    if (lo4 == 0) {
#pragma unroll
        for (int q = 0; q < 8; ++q) {
            const int tl = (q >> 2) * 16 + hi2 * 4 + (q & 3);
            ln_s[w][tl]  = s_[q];
            ln_ss[w][tl] = ss_[q];
        }
    }
    __syncthreads();

    float mu_[8], inv_[8];
#pragma unroll
    for (int q = 0; q < 8; ++q) {
        const int tl = (q >> 2) * 16 + hi2 * 4 + (q & 3);
        float S = 0.f, SS = 0.f;
#pragma unroll
        for (int ww = 0; ww < 8; ++ww) { S += ln_s[ww][tl]; SS += ln_ss[ww][tl]; }
        const float mu  = S * (1.f / DDIM);
        const float var = SS * (1.f / DDIM) - mu * mu;
        mu_[q]  = mu;
        inv_[q] = rsqrtf(var + LN_EPS);
    }

    // ---- write out ----
#pragma unroll
    for (int nf = 0; nf < 8; ++nf) {
        const int col = (w << 7) + (nf << 4) + lo4;
        const float g  = gamma[col];
        const float bb = beta[col];
#pragma unroll
        for (int m2 = 0; m2 < 2; ++m2) {
            const f32x4 v = acc[m2][nf];
#pragma unroll
            for (int r = 0; r < 4; ++r) {
                const int q   = m2 * 4 + r;
                const int tl  = m2 * 16 + hi2 * 4 + r;
                const int tok = tok0 + tl;
                if (tok < ntok)
                    out[(size_t)tok * DDIM + col] = (v[r] - mu_[q]) * inv_[q] * g + bb;
            }
        }
    }
}

// ---------------------------------------------------------------------------
extern "C" void kernel_launch(void* const* d_in, const int* in_sizes, int n_in,
                              void* d_out, int out_size, void* d_ws, size_t ws_size,
                              hipStream_t stream) {
    const int*   ids   = (const int*)  d_in[0];
    const float* bt    = (const float*)d_in[1];
    const float* pe    = (const float*)d_in[2];
    const float* W     = (const float*)d_in[3];
    const float* b_up  = (const float*)d_in[4];
    const float* gamma = (const float*)d_in[5];
    const float* beta  = (const float*)d_in[6];
    float* out = (float*)d_out;

    const int ntok = in_sizes[0] / PP;   // B*S = 16384

    char* ws = (char*)d_ws;
    unsigned short* t2b = (unsigned short*)(ws);        // 2 MB
    uint4*          wbb = (uint4*)(ws + (2 << 20));     // 512 KB (ks-major)
    unsigned short* Abf = (unsigned short*)(ws + (3 << 20)); // ntok*256*2 = 8 MB
    uint2*          Aq  = (uint2*)Abf;

    hipLaunchKernelGGL(k_prep, dim3(640), dim3(256), 0, stream, bt, pe, W, t2b, wbb);
    hipLaunchKernelGGL(k_gather, dim3((ntok + 3) / 4), dim3(256), 0, stream,
                       ids, t2b, Aq, ntok);
    hipLaunchKernelGGL(k_gemm, dim3((ntok + 31) / 32), dim3(512), 0, stream,
                       Abf, wbb, b_up, gamma, beta, out, ntok);
}